// Round 8
// baseline (371.293 us; speedup 1.0000x reference)
//
#include <hip/hip_runtime.h>
#include <cstdint>
#include <cstddef>

// ---------------------------------------------------------------------------
// TransformerLayer forward on MI355X (gfx950), bf16 MFMA pipeline.
// B=2, S=2048, D=1024, H=16, HD=64.  M = B*S = 4096 rows.
// Round 8: attention -> barrier-free main loop. Keys split across waves
// (this attention has no softmax, so key-sum is associative): each wave owns
// private K/V LDS dbuf + private P, counted per-wave vmcnt only; cross-wave
// merge via LDS atomicAdd at the end. GEMM: compile-time NT with n-minor
// block mapping (A-panel L2-resident per XCD chunk) + launch_bounds(256,3).
// ---------------------------------------------------------------------------

#define B_ 2
#define S_ 2048
#define D_ 1024
#define H_ 16
#define M_ 4096

typedef __attribute__((ext_vector_type(4))) float  f32x4;
typedef __attribute__((ext_vector_type(8))) __bf16 bf16x8;
typedef __attribute__((ext_vector_type(4))) __bf16 bf16x4;

#define WAITVM(N) asm volatile("s_waitcnt vmcnt(" #N ")" ::: "memory")

__device__ __forceinline__ void async16(const void* g, void* l) {
    __builtin_amdgcn_global_load_lds(
        (__attribute__((address_space(1))) void*)(g),
        (__attribute__((address_space(3))) void*)(l), 16, 0, 0);
}

// sigmoid(z)*tanh(z) == (1-u)/(1+u^2), u = exp(-z), z = s/32.
__device__ __forceinline__ float actf(float s) {
    float t = fminf(s * -0.045084223f, 21.6f);
    float u = __builtin_amdgcn_exp2f(t);
    return (1.f - u) * __builtin_amdgcn_rcpf(1.f + u * u);
}

// ---------------------------------------------------------------------------
// GEMM: C[M][Ntot] = epilogue(A[M][1024] @ Bt[Ntot][1024]^T + bias)
// Tile 128x64, BK=64, 4 waves (2x2), each wave 64x32 (acc 4x2).
// LDS 48 KB dbuf, counted WAITVM(6). NT compile-time; block mapping is
// n-minor (wg = m*NT + n) so consecutive wg (same XCD after swizzle) share
// the A-panel -> A L2-resident (1 MB per 64-wg chunk at NT=16).
// EPI: 0 bias->bf16 | 1 leaky(0.2)->bf16 | 2 aux+s*(.)->bf16 | 3 aux+s*(.)->f32
// ---------------------------------------------------------------------------
template <int EPI, int NT>
__global__ __launch_bounds__(256, 3) void gemm_k(
    const __bf16* __restrict__ A, const __bf16* __restrict__ Bt,
    const float* __restrict__ bias, const __bf16* __restrict__ aux,
    const float* __restrict__ scal, void* __restrict__ out)
{
    constexpr int K = D_;
    constexpr int Ntot = NT * 64;
    __shared__ __align__(16) __bf16 As[2][128][64];  // 32 KB
    __shared__ __align__(16) __bf16 Bs[2][64][64];   // 16 KB

    const int tid = threadIdx.x, lane = tid & 63, wid = tid >> 6;
    const int wr = wid >> 1, wc = wid & 1;
    const int cpx = (int)gridDim.x >> 3;            // grid % 8 == 0 always
    const int bid = (int)blockIdx.x;
    const int wg = (bid & 7) * cpx + (bid >> 3);    // XCD-bijective swizzle
    const int m0 = (wg / NT) * 128;                 // n-minor: A shared in chunk
    const int n0 = (wg % NT) * 64;
    const int frow = lane & 15;
    const int kb = (lane >> 4) * 16;                // k-group byte offset
    char* cAs = (char*)As; char* cBs = (char*)Bs;

    f32x4 acc[4][2] = {};

    auto stage = [&](int buf, int k0) {             // 6 loads / thread
#pragma unroll
        for (int i = 0; i < 4; ++i) {               // A tile: 16 KB
            const int o = tid * 16 + i * 4096;
            const int row = o >> 7;
            const int cb = (o & 127) ^ ((row & 7) << 4);
            async16(A + (size_t)(m0 + row) * K + k0 + (cb >> 1),
                    cAs + buf * 16384 + o);
        }
#pragma unroll
        for (int i = 0; i < 2; ++i) {               // B tile: 8 KB
            const int o = tid * 16 + i * 4096;
            const int row = o >> 7;
            const int cb = (o & 127) ^ ((row & 7) << 4);
            async16(Bt + (size_t)(n0 + row) * K + k0 + (cb >> 1),
                    cBs + buf * 8192 + o);
        }
    };

    auto compute = [&](int buf) {
        char* lA = cAs + buf * 16384;
        char* lB = cBs + buf * 8192;
#pragma unroll
        for (int kk = 0; kk < 2; ++kk) {
            bf16x8 af[4], bfr[2];
#pragma unroll
            for (int m = 0; m < 4; ++m) {
                const int r = wr * 64 + m * 16 + frow;
                af[m] = *(const bf16x8*)(lA + ((r * 128 + kk * 64 + kb) ^ ((r & 7) << 4)));
            }
#pragma unroll
            for (int n = 0; n < 2; ++n) {
                const int r = wc * 32 + n * 16 + frow;
                bfr[n] = *(const bf16x8*)(lB + ((r * 128 + kk * 64 + kb) ^ ((r & 7) << 4)));
            }
#pragma unroll
            for (int m = 0; m < 4; ++m)
#pragma unroll
                for (int n = 0; n < 2; ++n)
                    acc[m][n] = __builtin_amdgcn_mfma_f32_16x16x32_bf16(
                        af[m], bfr[n], acc[m][n], 0, 0, 0);
        }
    };

    stage(0, 0);
    stage(1, 64);
    WAITVM(6);                                  // buf0 complete (oldest 6)
    __builtin_amdgcn_sched_barrier(0);
    __builtin_amdgcn_s_barrier();

    for (int tp = 0; tp < 8; ++tp) {            // 16 K-steps, 2 per iter
        const int t0 = tp * 2;
        compute(0);
        __builtin_amdgcn_s_barrier();           // all waves done reading buf0
        if (t0 < 14) { stage(0, (t0 + 2) * 64); WAITVM(6); }
        else         { WAITVM(0); }             // last tile (in buf1) ready
        __builtin_amdgcn_sched_barrier(0);
        __builtin_amdgcn_s_barrier();
        compute(1);
        __builtin_amdgcn_s_barrier();           // all waves done reading buf1
        if (t0 < 14) { stage(1, (t0 + 3) * 64); WAITVM(6); }
        __builtin_amdgcn_sched_barrier(0);
        __builtin_amdgcn_s_barrier();
    }

    const float sv = (EPI >= 2) ? *scal : 0.f;
#pragma unroll
    for (int m = 0; m < 4; ++m) {
#pragma unroll
        for (int n = 0; n < 2; ++n) {
#pragma unroll
            for (int r = 0; r < 4; ++r) {
                const int row = m0 + wr * 64 + m * 16 + (lane >> 4) * 4 + r;
                const int col = n0 + wc * 32 + n * 16 + frow;
                const size_t idx = (size_t)row * Ntot + col;
                float v = acc[m][n][r] + bias[col];
                if constexpr (EPI == 0) {
                    ((__bf16*)out)[idx] = (__bf16)v;
                } else if constexpr (EPI == 1) {
                    v = v > 0.f ? v : 0.2f * v;
                    ((__bf16*)out)[idx] = (__bf16)v;
                } else if constexpr (EPI == 2) {
                    ((__bf16*)out)[idx] = (__bf16)((float)aux[idx] + sv * v);
                } else {
                    ((float*)out)[idx] = (float)aux[idx] + sv * v;
                }
            }
        }
    }
}

// ---------------------------------------------------------------------------
// Fused attention, barrier-free main loop (no softmax -> key-split is a
// plain associative sum). Block = (b, h, q-tile of 32), 2048 blocks,
// XCD-bijective. 4 waves; wave w owns key tiles kt = w*32 + t*128 (t=0..15),
// each KVBLK=32, staged into wave-PRIVATE LDS dbuf (K 32x64, V 64x32) via
// global_load_lds with per-wave counted vmcnt. P (32q x 32k bf16) also
// wave-private. Lane mappings identical to the verified r5-r7 kernel.
// Epilogue: waves atomicAdd partial ctx into f32 LDS scratch, one barrier,
// cooperative bf16 writeout. LDS 80 KB -> 2 blocks/CU.
// ---------------------------------------------------------------------------
__global__ __launch_bounds__(256, 2) void attn_k(
    const __bf16* __restrict__ Q, const __bf16* __restrict__ Kmat,
    const __bf16* __restrict__ VT, __bf16* __restrict__ CTX, int ld)
{
    __shared__ __align__(16) char smem[81920];
    char* cK = smem;                       // [wid][buf][4096]  K: [32 key][64 hd]
    char* cV = smem + 32768;               // [wid][buf][4096]  V: [64 d][32 key]
    char* cP = smem + 65536;               // [wid][2048]       P: [32 q][32 key]
    float* sAcc = (float*)(smem + 73728);  // [32 q][64 d] f32 scratch

    const int tid = threadIdx.x, wid = tid >> 6, lane = tid & 63;
    const int bid = (int)blockIdx.x;
    const int wg = (bid & 7) * 256 + (bid >> 3);    // 2048 blocks, bijective
    const int qt = wg & 63, h = (wg >> 6) & 15, b = wg >> 10;
    const int q0 = qt * 32;
    const int frow = lane & 15, g = lane >> 4;
    const int kg8 = g * 8;

    const __bf16* qbase = Q    + (size_t)(b * S_ + q0) * ld + h * 64;
    const __bf16* kbase = Kmat + (size_t)b * S_ * ld + h * 64;
    const __bf16* vbase = VT   + (size_t)(b * H_ + h) * 64 * S_;

    // zero the merge scratch (2048 f32)
#pragma unroll
    for (int i = 0; i < 2; ++i)
        ((f32x4*)sAcc)[tid + i * 256] = f32x4{0.f, 0.f, 0.f, 0.f};
    __syncthreads();

    // Q fragments: all 32 q-rows of this block, in regs (B-operand layout)
    bf16x8 qf[2][2];
#pragma unroll
    for (int qf_ = 0; qf_ < 2; ++qf_)
#pragma unroll
        for (int kk = 0; kk < 2; ++kk)
            qf[qf_][kk] = *(const bf16x8*)(qbase +
                (size_t)(16 * qf_ + frow) * ld + kk * 32 + kg8);
    __builtin_amdgcn_sched_barrier(0);   // qf loads oldest in vmcnt queue

    auto stK = [&](int buf, int kt) {               // 4 KB, 4 issues
#pragma unroll
        for (int i = 0; i < 4; ++i) {
            const int o = lane * 16 + i * 1024;
            const int row = o >> 7;                  // key row, 128 B
            const int cb = (o & 127) ^ ((row & 7) << 4);
            async16(kbase + (size_t)(kt + row) * ld + (cb >> 1),
                    cK + wid * 8192 + buf * 4096 + o);
        }
    };
    auto stV = [&](int buf, int kt) {               // 4 KB, 4 issues
#pragma unroll
        for (int i = 0; i < 4; ++i) {
            const int o = lane * 16 + i * 1024;
            const int row = o >> 6;                  // d row, 64 B
            const int cb = (o & 63) ^ ((row & 3) << 4);
            async16(vbase + (size_t)row * S_ + kt + (cb >> 1),
                    cV + wid * 8192 + buf * 4096 + o);
        }
    };

    const int kt0 = wid * 32;                       // this wave's key offset
    stK(0, kt0);        stV(0, kt0);
    stK(1, kt0 + 128);  stV(1, kt0 + 128);
    WAITVM(8);                  // qf(4) + tile0 K/V(8) done of 20 outstanding

    f32x4 acc[2][4] = {};

    for (int t = 0; t < 16; ++t) {
        char* bK = cK + wid * 8192 + (t & 1) * 4096;
        char* bV = cV + wid * 8192 + (t & 1) * 4096;
        char* bP = cP + wid * 2048;

        // ---- S^T = K Q^T : scc[kf][qf], lane = (key 16kf+4g+r, q 16qf+frow)
        f32x4 scc[2][2] = {};
#pragma unroll
        for (int kk = 0; kk < 2; ++kk)
#pragma unroll
            for (int kf_ = 0; kf_ < 2; ++kf_) {
                const int row = 16 * kf_ + frow;
                bf16x8 kfv = *(const bf16x8*)(bK +
                    (row * 128 + ((kk * 64 + g * 16) ^ ((row & 7) << 4))));
#pragma unroll
                for (int qf_ = 0; qf_ < 2; ++qf_)
                    scc[kf_][qf_] = __builtin_amdgcn_mfma_f32_16x16x32_bf16(
                        kfv, qf[qf_][kk], scc[kf_][qf_], 0, 0, 0);
            }

        // ---- activation + packed b64 P-writes (wave-private P)
#pragma unroll
        for (int kf_ = 0; kf_ < 2; ++kf_)
#pragma unroll
            for (int qf_ = 0; qf_ < 2; ++qf_) {
                bf16x4 pw;
#pragma unroll
                for (int r = 0; r < 4; ++r) pw[r] = (__bf16)actf(scc[kf_][qf_][r]);
                const int row = 16 * qf_ + frow;
                *(bf16x4*)(bP + row * 64 +
                    ((kf_ * 32 + g * 8) ^ ((row & 3) << 4))) = pw;
            }

        // ---- gather PV operands
        bf16x8 pa[2], vf[4];
#pragma unroll
        for (int qf_ = 0; qf_ < 2; ++qf_) {
            const int row = 16 * qf_ + frow;
            pa[qf_] = *(const bf16x8*)(bP + row * 64 +
                ((g * 16) ^ ((row & 3) << 4)));
        }
#pragma unroll
        for (int df = 0; df < 4; ++df) {
            const int row = 16 * df + frow;
            vf[df] = *(const bf16x8*)(bV + row * 64 +
                ((g * 16) ^ ((row & 3) << 4)));
        }
        asm volatile("s_waitcnt lgkmcnt(0)" ::: "memory");
        __builtin_amdgcn_sched_barrier(0);
        if (t < 14) {                       // restage this buf for tile t+2
            stK(t & 1, kt0 + (t + 2) * 128);
            stV(t & 1, kt0 + (t + 2) * 128);
        }
        // ---- ctx += P @ V
#pragma unroll
        for (int qf_ = 0; qf_ < 2; ++qf_)
#pragma unroll
            for (int df = 0; df < 4; ++df)
                acc[qf_][df] = __builtin_amdgcn_mfma_f32_16x16x32_bf16(
                    pa[qf_], vf[df], acc[qf_][df], 0, 0, 0);
        if (t < 14) { WAITVM(8); }          // tile t+1 ready, t+2 in flight
        else        { WAITVM(0); }          // drain for final tile
    }

    // ---- cross-wave merge: atomicAdd partials, then cooperative writeout
#pragma unroll
    for (int qf_ = 0; qf_ < 2; ++qf_)
#pragma unroll
        for (int df = 0; df < 4; ++df)
#pragma unroll
            for (int r = 0; r < 4; ++r)
                atomicAdd(&sAcc[(16 * qf_ + 4 * g + r) * 64 + 16 * df + frow],
                          acc[qf_][df][r]);
    __syncthreads();
#pragma unroll
    for (int i = 0; i < 2; ++i) {
        const int idx4 = (tid + i * 256) * 4;
        const int q = idx4 >> 6, dc = idx4 & 63;
        f32x4 v = *(const f32x4*)&sAcc[idx4];
        bf16x4 o4;
        o4[0] = (__bf16)v[0]; o4[1] = (__bf16)v[1];
        o4[2] = (__bf16)v[2]; o4[3] = (__bf16)v[3];
        *(bf16x4*)&CTX[(size_t)(b * S_ + q0 + q) * D_ + h * 64 + dc] = o4;
    }
}

// ---------------------------------------------------------------------------
struct WPack { const float* w[7]; };

__global__ __launch_bounds__(256) void conv_transpose_w(WPack p, __bf16* out) {
    __shared__ float t[32][33];
    const float* W = p.w[blockIdx.z];
    __bf16* o = out + (size_t)blockIdx.z * D_ * D_;
    const int c0 = blockIdx.x * 32, r0 = blockIdx.y * 32;
    const int tx = threadIdx.x, ty = threadIdx.y;
#pragma unroll
    for (int i = 0; i < 4; ++i)
        t[ty + i * 8][tx] = W[(size_t)(r0 + ty + i * 8) * D_ + c0 + tx];
    __syncthreads();
#pragma unroll
    for (int i = 0; i < 4; ++i)
        o[(size_t)(c0 + ty + i * 8) * D_ + r0 + tx] = (__bf16)t[tx][ty + i * 8];
}

__global__ __launch_bounds__(256) void conv_bf16(
    const float* __restrict__ in, __bf16* __restrict__ out, int n4)
{
    const int i = blockIdx.x * blockDim.x + threadIdx.x;
    if (i < n4) {
        f32x4 v = ((const f32x4*)in)[i];
        bf16x4 o;
        o[0] = (__bf16)v[0]; o[1] = (__bf16)v[1];
        o[2] = (__bf16)v[2]; o[3] = (__bf16)v[3];
        ((bf16x4*)out)[i] = o;
    }
}

__global__ __launch_bounds__(256) void bcat_k(
    const float* __restrict__ bq, const float* __restrict__ bk,
    const float* __restrict__ bv, float* __restrict__ o)
{
    const int i = blockIdx.x * 256 + threadIdx.x;   // 0..3071
    o[i] = i < 1024 ? bq[i] : (i < 2048 ? bk[i - 1024] : bv[i - 2048]);
}

// V rows of QKV [B*S][ld] -> VT[(b*D + col)][S]
__global__ __launch_bounds__(256) void transpose_v(
    const __bf16* __restrict__ V, __bf16* __restrict__ VT, int ld)
{
    __shared__ __bf16 t[32][33];
    const int s0 = blockIdx.x * 32, c0 = blockIdx.y * 32, b = blockIdx.z;
    const int tx = threadIdx.x, ty = threadIdx.y;
#pragma unroll
    for (int i = 0; i < 4; ++i)
        t[ty + i * 8][tx] = V[(size_t)(b * S_ + s0 + ty + i * 8) * ld + c0 + tx];
    __syncthreads();
#pragma unroll
    for (int i = 0; i < 4; ++i)
        VT[(size_t)(b * D_ + c0 + ty + i * 8) * S_ + s0 + tx] = t[tx][ty + i * 8];
}

// ---------------------------------------------------------------------------
extern "C" void kernel_launch(void* const* d_in, const int* in_sizes, int n_in,
                              void* d_out, int out_size, void* d_ws, size_t ws_size,
                              hipStream_t stream) {
    const float* x    = (const float*)d_in[0];
    const float* W_in = (const float*)d_in[1];
    const float* b_in = (const float*)d_in[2];
    const float* Wq   = (const float*)d_in[3];
    const float* bq   = (const float*)d_in[4];
    const float* Wk   = (const float*)d_in[5];
    const float* bk   = (const float*)d_in[6];
    const float* Wv   = (const float*)d_in[7];
    const float* bv   = (const float*)d_in[8];
    const float* Wo   = (const float*)d_in[9];
    const float* bo   = (const float*)d_in[10];
    const float* W1   = (const float*)d_in[11];
    const float* b1   = (const float*)d_in[12];
    const float* W2   = (const float*)d_in[13];
    const float* b2   = (const float*)d_in[14];
    const float* s_att = (const float*)d_in[15];
    const float* s_ff  = (const float*)d_in[16];

    char* ws = (char*)d_ws;
    const size_t WB = (size_t)D_ * D_ * 2;       // 2 MB / bf16 weight
    const size_t MB = (size_t)M_ * D_ * 2;       // 8 MB / bf16 activation
    __bf16* WT   = (__bf16*)(ws);                           // 14 MB
    __bf16* Hb   = (__bf16*)(ws + 7 * WB);                  // 8 MB
    __bf16* QKVb = (__bf16*)(ws + 7 * WB + MB);             // 24 MB
    __bf16* VTb  = (__bf16*)(ws + 7 * WB + 4 * MB);         // 8 MB
    __bf16* Xb   = (__bf16*)(ws + 7 * WB + 5 * MB);         // 8 MB
    float*  bcat = (float*)VTb;       // alias: bcat dead before VTb written
    __bf16* CTXb = Xb;                // x dead after first GEMM
    __bf16* LATb = QKVb;              // qkv dead after attention
    __bf16* FF1b = QKVb + (size_t)M_ * D_;
    auto WTi = [&](int i) { return WT + (size_t)i * D_ * D_; };

    WPack wp;
    wp.w[0] = W_in; wp.w[1] = Wq; wp.w[2] = Wk; wp.w[3] = Wv;
    wp.w[4] = Wo;   wp.w[5] = W1; wp.w[6] = W2;
    conv_transpose_w<<<dim3(32, 32, 7), dim3(32, 8), 0, stream>>>(wp, WT);
    conv_bf16<<<dim3(4096), dim3(256), 0, stream>>>(x, Xb, (M_ * D_) / 4);
    bcat_k<<<dim3(12), dim3(256), 0, stream>>>(bq, bk, bv, bcat);

    // h = x @ W_in + b_in            (32 m x 16 n = 512 blocks)
    gemm_k<0, 16><<<dim3(512), dim3(256), 0, stream>>>(
        Xb, WTi(0), b_in, nullptr, nullptr, Hb);
    // qkv = h @ [Wq|Wk|Wv] + bcat    (N=3072: 32 x 48 = 1536 blocks)
    gemm_k<0, 48><<<dim3(1536), dim3(256), 0, stream>>>(
        Hb, WTi(1), bcat, nullptr, nullptr, QKVb);
    transpose_v<<<dim3(64, 32, 2), dim3(32, 8), 0, stream>>>(
        QKVb + 2 * D_, VTb, 3 * D_);
    attn_k<<<dim3(2048), dim3(256), 0, stream>>>(
        QKVb, QKVb + D_, VTb, CTXb, 3 * D_);
    // latent = h + s_att * (ctx @ Wo + bo)
    gemm_k<2, 16><<<dim3(512), dim3(256), 0, stream>>>(
        CTXb, WTi(4), bo, Hb, s_att, LATb);
    // ff1 = leaky_relu(latent @ W1 + b1)
    gemm_k<1, 16><<<dim3(512), dim3(256), 0, stream>>>(
        LATb, WTi(5), b1, nullptr, nullptr, FF1b);
    // out = latent + s_ff * (ff1 @ W2 + b2)  (f32)
    gemm_k<3, 16><<<dim3(512), dim3(256), 0, stream>>>(
        FF1b, WTi(6), b2, LATb, s_ff, d_out);
}

// Round 9
// 271.881 us; speedup vs baseline: 1.3656x; 1.3656x over previous
//
#include <hip/hip_runtime.h>
#include <cstdint>
#include <cstddef>

// ---------------------------------------------------------------------------
// TransformerLayer forward on MI355X (gfx950), bf16 MFMA pipeline.
// B=2, S=2048, D=1024, H=16, HD=64.  M = B*S = 4096 rows.
// Round 9: attention reverted to proven r7 kernel (r8 wave-private layout
// quadrupled bank conflicts: 64B rows alias banks; lesson learned).
// N=1024 GEMMs keep r8 structure (n-minor + lb(256,3), proven -8%).
// QKV GEMM -> 128x128 tile, 64x64/wave (LDS:MFMA 1.6:1 vs 2.5:1) with
// 2 blocks/CU (grid 768), counted vmcnt(8).
// ---------------------------------------------------------------------------

#define B_ 2
#define S_ 2048
#define D_ 1024
#define H_ 16
#define M_ 4096

typedef __attribute__((ext_vector_type(4))) float  f32x4;
typedef __attribute__((ext_vector_type(8))) __bf16 bf16x8;
typedef __attribute__((ext_vector_type(4))) __bf16 bf16x4;

#define WAITVM(N) asm volatile("s_waitcnt vmcnt(" #N ")" ::: "memory")

__device__ __forceinline__ void async16(const void* g, void* l) {
    __builtin_amdgcn_global_load_lds(
        (__attribute__((address_space(1))) void*)(g),
        (__attribute__((address_space(3))) void*)(l), 16, 0, 0);
}

// sigmoid(z)*tanh(z) == (1-u)/(1+u^2), u = exp(-z), z = s/32.
__device__ __forceinline__ float actf(float s) {
    float t = fminf(s * -0.045084223f, 21.6f);
    float u = __builtin_amdgcn_exp2f(t);
    return (1.f - u) * __builtin_amdgcn_rcpf(1.f + u * u);
}

// ---------------------------------------------------------------------------
// GEMM (N=1024 path): C[M][1024] = epi(A @ Bt^T + bias).  Tile 128x64,
// 4 waves x (64x32), 48 KB LDS dbuf, counted WAITVM(6), n-minor mapping.
// EPI: 0 bias->bf16 | 1 leaky(0.2)->bf16 | 2 aux+s*(.)->bf16 | 3 aux+s*(.)->f32
// ---------------------------------------------------------------------------
template <int EPI, int NT>
__global__ __launch_bounds__(256, 3) void gemm_k(
    const __bf16* __restrict__ A, const __bf16* __restrict__ Bt,
    const float* __restrict__ bias, const __bf16* __restrict__ aux,
    const float* __restrict__ scal, void* __restrict__ out)
{
    constexpr int K = D_;
    constexpr int Ntot = NT * 64;
    __shared__ __align__(16) __bf16 As[2][128][64];  // 32 KB
    __shared__ __align__(16) __bf16 Bs[2][64][64];   // 16 KB

    const int tid = threadIdx.x, lane = tid & 63, wid = tid >> 6;
    const int wr = wid >> 1, wc = wid & 1;
    const int cpx = (int)gridDim.x >> 3;
    const int bid = (int)blockIdx.x;
    const int wg = (bid & 7) * cpx + (bid >> 3);    // XCD-bijective swizzle
    const int m0 = (wg / NT) * 128;                 // n-minor: A shared in chunk
    const int n0 = (wg % NT) * 64;
    const int frow = lane & 15;
    const int kb = (lane >> 4) * 16;
    char* cAs = (char*)As; char* cBs = (char*)Bs;

    f32x4 acc[4][2] = {};

    auto stage = [&](int buf, int k0) {             // 6 loads / thread
#pragma unroll
        for (int i = 0; i < 4; ++i) {               // A tile: 16 KB
            const int o = tid * 16 + i * 4096;
            const int row = o >> 7;
            const int cb = (o & 127) ^ ((row & 7) << 4);
            async16(A + (size_t)(m0 + row) * K + k0 + (cb >> 1),
                    cAs + buf * 16384 + o);
        }
#pragma unroll
        for (int i = 0; i < 2; ++i) {               // B tile: 8 KB
            const int o = tid * 16 + i * 4096;
            const int row = o >> 7;
            const int cb = (o & 127) ^ ((row & 7) << 4);
            async16(Bt + (size_t)(n0 + row) * K + k0 + (cb >> 1),
                    cBs + buf * 8192 + o);
        }
    };

    auto compute = [&](int buf) {
        char* lA = cAs + buf * 16384;
        char* lB = cBs + buf * 8192;
#pragma unroll
        for (int kk = 0; kk < 2; ++kk) {
            bf16x8 af[4], bfr[2];
#pragma unroll
            for (int m = 0; m < 4; ++m) {
                const int r = wr * 64 + m * 16 + frow;
                af[m] = *(const bf16x8*)(lA + ((r * 128 + kk * 64 + kb) ^ ((r & 7) << 4)));
            }
#pragma unroll
            for (int n = 0; n < 2; ++n) {
                const int r = wc * 32 + n * 16 + frow;
                bfr[n] = *(const bf16x8*)(lB + ((r * 128 + kk * 64 + kb) ^ ((r & 7) << 4)));
            }
#pragma unroll
            for (int m = 0; m < 4; ++m)
#pragma unroll
                for (int n = 0; n < 2; ++n)
                    acc[m][n] = __builtin_amdgcn_mfma_f32_16x16x32_bf16(
                        af[m], bfr[n], acc[m][n], 0, 0, 0);
        }
    };

    stage(0, 0);
    stage(1, 64);
    WAITVM(6);
    __builtin_amdgcn_sched_barrier(0);
    __builtin_amdgcn_s_barrier();

    for (int tp = 0; tp < 8; ++tp) {
        const int t0 = tp * 2;
        compute(0);
        __builtin_amdgcn_s_barrier();
        if (t0 < 14) { stage(0, (t0 + 2) * 64); WAITVM(6); }
        else         { WAITVM(0); }
        __builtin_amdgcn_sched_barrier(0);
        __builtin_amdgcn_s_barrier();
        compute(1);
        __builtin_amdgcn_s_barrier();
        if (t0 < 14) { stage(1, (t0 + 3) * 64); WAITVM(6); }
        __builtin_amdgcn_sched_barrier(0);
        __builtin_amdgcn_s_barrier();
    }

    const float sv = (EPI >= 2) ? *scal : 0.f;
#pragma unroll
    for (int m = 0; m < 4; ++m) {
#pragma unroll
        for (int n = 0; n < 2; ++n) {
#pragma unroll
            for (int r = 0; r < 4; ++r) {
                const int row = m0 + wr * 64 + m * 16 + (lane >> 4) * 4 + r;
                const int col = n0 + wc * 32 + n * 16 + frow;
                const size_t idx = (size_t)row * Ntot + col;
                float v = acc[m][n][r] + bias[col];
                if constexpr (EPI == 0) {
                    ((__bf16*)out)[idx] = (__bf16)v;
                } else if constexpr (EPI == 1) {
                    v = v > 0.f ? v : 0.2f * v;
                    ((__bf16*)out)[idx] = (__bf16)v;
                } else if constexpr (EPI == 2) {
                    ((__bf16*)out)[idx] = (__bf16)((float)aux[idx] + sv * v);
                } else {
                    ((float*)out)[idx] = (float)aux[idx] + sv * v;
                }
            }
        }
    }
}

// ---------------------------------------------------------------------------
// QKV GEMM: out[M][3072] = A @ Bt^T + bias.  Tile 128x128, 4 waves (2x2)
// each 64x64 (acc 4x4): LDS:MFMA ratio 1.6:1 (vs 2.5:1 for 64x32).
// 64 KB LDS dbuf -> 2 blocks/CU (grid 768). Counted WAITVM(8).
// ---------------------------------------------------------------------------
__global__ __launch_bounds__(256, 2) void gemm_qkv(
    const __bf16* __restrict__ A, const __bf16* __restrict__ Bt,
    const float* __restrict__ bias, __bf16* __restrict__ out)
{
    constexpr int K = D_;
    constexpr int NT = 24;                          // 3072 / 128
    constexpr int Ntot = 3 * D_;
    __shared__ __align__(16) __bf16 As[2][128][64]; // 32 KB
    __shared__ __align__(16) __bf16 Bs[2][128][64]; // 32 KB

    const int tid = threadIdx.x, lane = tid & 63, wid = tid >> 6;
    const int wr = wid >> 1, wc = wid & 1;
    const int cpx = (int)gridDim.x >> 3;            // 96
    const int bid = (int)blockIdx.x;
    const int wg = (bid & 7) * cpx + (bid >> 3);
    const int m0 = (wg / NT) * 128;
    const int n0 = (wg % NT) * 128;
    const int frow = lane & 15;
    const int kb = (lane >> 4) * 16;
    char* cAs = (char*)As; char* cBs = (char*)Bs;

    f32x4 acc[4][4] = {};

    auto stage = [&](int buf, int k0) {             // 8 loads / thread
#pragma unroll
        for (int i = 0; i < 4; ++i) {
            const int o = tid * 16 + i * 4096;
            const int row = o >> 7;
            const int cb = (o & 127) ^ ((row & 7) << 4);
            async16(A + (size_t)(m0 + row) * K + k0 + (cb >> 1),
                    cAs + buf * 16384 + o);
            async16(Bt + (size_t)(n0 + row) * K + k0 + (cb >> 1),
                    cBs + buf * 16384 + o);
        }
    };

    auto compute = [&](int buf) {
        char* lA = cAs + buf * 16384;
        char* lB = cBs + buf * 16384;
#pragma unroll
        for (int kk = 0; kk < 2; ++kk) {
            bf16x8 af[4], bfr[4];
#pragma unroll
            for (int m = 0; m < 4; ++m) {
                const int r = wr * 64 + m * 16 + frow;
                af[m] = *(const bf16x8*)(lA + ((r * 128 + kk * 64 + kb) ^ ((r & 7) << 4)));
            }
#pragma unroll
            for (int n = 0; n < 4; ++n) {
                const int r = wc * 64 + n * 16 + frow;
                bfr[n] = *(const bf16x8*)(lB + ((r * 128 + kk * 64 + kb) ^ ((r & 7) << 4)));
            }
#pragma unroll
            for (int m = 0; m < 4; ++m)
#pragma unroll
                for (int n = 0; n < 4; ++n)
                    acc[m][n] = __builtin_amdgcn_mfma_f32_16x16x32_bf16(
                        af[m], bfr[n], acc[m][n], 0, 0, 0);
        }
    };

    stage(0, 0);
    stage(1, 64);
    WAITVM(8);
    __builtin_amdgcn_sched_barrier(0);
    __builtin_amdgcn_s_barrier();

    for (int tp = 0; tp < 8; ++tp) {
        const int t0 = tp * 2;
        compute(0);
        __builtin_amdgcn_s_barrier();
        if (t0 < 14) { stage(0, (t0 + 2) * 64); WAITVM(8); }
        else         { WAITVM(0); }
        __builtin_amdgcn_sched_barrier(0);
        __builtin_amdgcn_s_barrier();
        compute(1);
        __builtin_amdgcn_s_barrier();
        if (t0 < 14) { stage(1, (t0 + 3) * 64); WAITVM(8); }
        __builtin_amdgcn_sched_barrier(0);
        __builtin_amdgcn_s_barrier();
    }

#pragma unroll
    for (int m = 0; m < 4; ++m) {
#pragma unroll
        for (int n = 0; n < 4; ++n) {
#pragma unroll
            for (int r = 0; r < 4; ++r) {
                const int row = m0 + wr * 64 + m * 16 + (lane >> 4) * 4 + r;
                const int col = n0 + wc * 64 + n * 16 + frow;
                out[(size_t)row * Ntot + col] = (__bf16)(acc[m][n][r] + bias[col]);
            }
        }
    }
}

// ---------------------------------------------------------------------------
// Fused attention — byte-identical to the verified round-7 kernel.
// XCD-bijective 1D grid (1024 blocks), 4 waves x 16 q-rows, KVBLK=64 dbuf
// with counted vmcnt, swapped QK^T + packed b64 P-writes, wave-private Ps,
// s_setprio(1) around MFMA clusters. 40 KB LDS, 4 blocks/CU.
// ---------------------------------------------------------------------------
__global__ __launch_bounds__(256, 4) void attn_k(
    const __bf16* __restrict__ Q, const __bf16* __restrict__ Kmat,
    const __bf16* __restrict__ VT, __bf16* __restrict__ CTX, int ld)
{
    __shared__ __align__(16) __bf16 Ks[2][64][64];  // 16 KB [buf][key][hd]
    __shared__ __align__(16) __bf16 Vs[2][64][64];  // 16 KB [buf][d][key]
    __shared__ __align__(16) __bf16 Ps[64][64];     //  8 KB [q][key]

    const int tid = threadIdx.x, wid = tid >> 6, lane = tid & 63;
    const int bid = (int)blockIdx.x;
    const int wg = (bid & 7) * 128 + (bid >> 3);    // 1024 blocks, bijective
    const int qt = wg & 31, h = (wg >> 5) & 15, b = wg >> 9;
    const int q0 = qt * 64;
    const int frow = lane & 15, g = lane >> 4;
    const int kg8 = g * 8, kb = g * 16;
    const int qrow = wid * 16 + frow;               // this lane's q row

    const __bf16* qbase = Q    + (size_t)(b * S_ + q0) * ld + h * 64;
    const __bf16* kbase = Kmat + (size_t)b * S_ * ld + h * 64;
    const __bf16* vbase = VT   + (size_t)(b * H_ + h) * 64 * S_;

    bf16x8 qf[2];
#pragma unroll
    for (int kk = 0; kk < 2; ++kk)
        qf[kk] = *(const bf16x8*)(qbase + (size_t)qrow * ld + kk * 32 + kg8);
    __builtin_amdgcn_sched_barrier(0);   // pin qf loads before staging (vmcnt order)

    f32x4 octx[4] = {};
    char* cKs = (char*)Ks; char* cVs = (char*)Vs; char* lPs = (char*)Ps;

    auto stageKV = [&](int buf, int kt) {           // 4 loads / thread
#pragma unroll
        for (int i = 0; i < 2; ++i) {
            const int o = tid * 16 + i * 4096;      // 0..8KB
            const int row = o >> 7;
            const int cb = (o & 127) ^ ((row & 7) << 4);
            async16(kbase + (size_t)(kt + row) * ld + (cb >> 1),
                    cKs + buf * 8192 + o);
            async16(vbase + (size_t)row * S_ + kt + (cb >> 1),
                    cVs + buf * 8192 + o);
        }
    };

    auto computeTile = [&](char* lKs, char* lVs) {
        // ---- S^T = K Q^T: lane holds P[key=16n+4g+r][q=qrow]
        f32x4 scc[4] = {};
        __builtin_amdgcn_s_setprio(1);
#pragma unroll
        for (int kk = 0; kk < 2; ++kk) {
            bf16x8 kf[4];
#pragma unroll
            for (int n = 0; n < 4; ++n) {
                const int r = n * 16 + frow;
                kf[n] = *(const bf16x8*)(lKs + ((r * 128 + kk * 64 + kb) ^ ((r & 7) << 4)));
            }
#pragma unroll
            for (int n = 0; n < 4; ++n)
                scc[n] = __builtin_amdgcn_mfma_f32_16x16x32_bf16(
                    kf[n], qf[kk], scc[n], 0, 0, 0);
        }
        __builtin_amdgcn_s_setprio(0);
        // ---- activation + packed b64 P-write (4 consecutive keys/write)
#pragma unroll
        for (int n = 0; n < 4; ++n) {
            bf16x4 pw;
#pragma unroll
            for (int r = 0; r < 4; ++r) pw[r] = (__bf16)actf(scc[n][r]);
            *(bf16x4*)(lPs + ((qrow * 128 + n * 32 + g * 8) ^ ((qrow & 7) << 4))) = pw;
        }
        // ---- ctx += P @ V  (wave-private P rows: no barrier)
        __builtin_amdgcn_s_setprio(1);
#pragma unroll
        for (int ks = 0; ks < 2; ++ks) {
            bf16x8 pf = *(const bf16x8*)(lPs +
                ((qrow * 128 + ks * 64 + kb) ^ ((qrow & 7) << 4)));
            bf16x8 vf[4];
#pragma unroll
            for (int nd = 0; nd < 4; ++nd) {
                const int rd = nd * 16 + frow;
                vf[nd] = *(const bf16x8*)(lVs + ((rd * 128 + ks * 64 + kb) ^ ((rd & 7) << 4)));
            }
#pragma unroll
            for (int nd = 0; nd < 4; ++nd)
                octx[nd] = __builtin_amdgcn_mfma_f32_16x16x32_bf16(
                    pf, vf[nd], octx[nd], 0, 0, 0);
        }
        __builtin_amdgcn_s_setprio(0);
    };

    stageKV(0, 0);
    stageKV(1, 64);
    WAITVM(4);                                  // buf0 ready (oldest 4)
    __builtin_amdgcn_sched_barrier(0);
    __builtin_amdgcn_s_barrier();

    for (int it = 0; it < 16; ++it) {           // 32 key-tiles, 2 per iter
        const int kt0 = it * 128;
        computeTile(cKs, cVs);                  // buf0 = tile kt0
        __builtin_amdgcn_s_barrier();           // all waves done with buf0
        if (it < 15) { stageKV(0, kt0 + 128); WAITVM(4); }
        else         { WAITVM(0); }             // last tile (buf1) ready
        __builtin_amdgcn_sched_barrier(0);
        __builtin_amdgcn_s_barrier();
        computeTile(cKs + 8192, cVs + 8192);    // buf1 = tile kt0+64
        __builtin_amdgcn_s_barrier();
        if (it < 15) { stageKV(1, kt0 + 192); WAITVM(4); }
        __builtin_amdgcn_sched_barrier(0);
        __builtin_amdgcn_s_barrier();
    }

#pragma unroll
    for (int nd = 0; nd < 4; ++nd)
#pragma unroll
        for (int r = 0; r < 4; ++r) {
            const int row = q0 + wid * 16 + g * 4 + r;
            const int col = h * 64 + nd * 16 + frow;
            CTX[(size_t)(b * S_ + row) * D_ + col] = (__bf16)octx[nd][r];
        }
}

// ---------------------------------------------------------------------------
struct WPack { const float* w[7]; };

__global__ __launch_bounds__(256) void conv_transpose_w(WPack p, __bf16* out) {
    __shared__ float t[32][33];
    const float* W = p.w[blockIdx.z];
    __bf16* o = out + (size_t)blockIdx.z * D_ * D_;
    const int c0 = blockIdx.x * 32, r0 = blockIdx.y * 32;
    const int tx = threadIdx.x, ty = threadIdx.y;
#pragma unroll
    for (int i = 0; i < 4; ++i)
        t[ty + i * 8][tx] = W[(size_t)(r0 + ty + i * 8) * D_ + c0 + tx];
    __syncthreads();
#pragma unroll
    for (int i = 0; i < 4; ++i)
        o[(size_t)(c0 + ty + i * 8) * D_ + r0 + tx] = (__bf16)t[tx][ty + i * 8];
}

__global__ __launch_bounds__(256) void conv_bf16(
    const float* __restrict__ in, __bf16* __restrict__ out, int n4)
{
    const int i = blockIdx.x * blockDim.x + threadIdx.x;
    if (i < n4) {
        f32x4 v = ((const f32x4*)in)[i];
        bf16x4 o;
        o[0] = (__bf16)v[0]; o[1] = (__bf16)v[1];
        o[2] = (__bf16)v[2]; o[3] = (__bf16)v[3];
        ((bf16x4*)out)[i] = o;
    }
}

__global__ __launch_bounds__(256) void bcat_k(
    const float* __restrict__ bq, const float* __restrict__ bk,
    const float* __restrict__ bv, float* __restrict__ o)
{
    const int i = blockIdx.x * 256 + threadIdx.x;   // 0..3071
    o[i] = i < 1024 ? bq[i] : (i < 2048 ? bk[i - 1024] : bv[i - 2048]);
}

// V rows of QKV [B*S][ld] -> VT[(b*D + col)][S]
__global__ __launch_bounds__(256) void transpose_v(
    const __bf16* __restrict__ V, __bf16* __restrict__ VT, int ld)
{
    __shared__ __bf16 t[32][33];
    const int s0 = blockIdx.x * 32, c0 = blockIdx.y * 32, b = blockIdx.z;
    const int tx = threadIdx.x, ty = threadIdx.y;
#pragma unroll
    for (int i = 0; i < 4; ++i)
        t[ty + i * 8][tx] = V[(size_t)(b * S_ + s0 + ty + i * 8) * ld + c0 + tx];
    __syncthreads();
#pragma unroll
    for (int i = 0; i < 4; ++i)
        VT[(size_t)(b * D_ + c0 + ty + i * 8) * S_ + s0 + tx] = t[tx][ty + i * 8];
}

// ---------------------------------------------------------------------------
extern "C" void kernel_launch(void* const* d_in, const int* in_sizes, int n_in,
                              void* d_out, int out_size, void* d_ws, size_t ws_size,
                              hipStream_t stream) {
    const float* x    = (const float*)d_in[0];
    const float* W_in = (const float*)d_in[1];
    const float* b_in = (const float*)d_in[2];
    const float* Wq   = (const float*)d_in[3];
    const float* bq   = (const float*)d_in[4];
    const float* Wk   = (const float*)d_in[5];
    const float* bk   = (const float*)d_in[6];
    const float* Wv   = (const float*)d_in[7];
    const float* bv   = (const float*)d_in[8];
    const float* Wo   = (const float*)d_in[9];
    const float* bo   = (const float*)d_in[10];
    const float* W1   = (const float*)d_in[11];
    const float* b1   = (const float*)d_in[12];
    const float* W2   = (const float*)d_in[13];
    const float* b2   = (const float*)d_in[14];
    const float* s_att = (const float*)d_in[15];
    const float* s_ff  = (const float*)d_in[16];

    char* ws = (char*)d_ws;
    const size_t WB = (size_t)D_ * D_ * 2;       // 2 MB / bf16 weight
    const size_t MB = (size_t)M_ * D_ * 2;       // 8 MB / bf16 activation
    __bf16* WT   = (__bf16*)(ws);                           // 14 MB
    __bf16* Hb   = (__bf16*)(ws + 7 * WB);                  // 8 MB
    __bf16* QKVb = (__bf16*)(ws + 7 * WB + MB);             // 24 MB
    __bf16* VTb  = (__bf16*)(ws + 7 * WB + 4 * MB);         // 8 MB
    __bf16* Xb   = (__bf16*)(ws + 7 * WB + 5 * MB);         // 8 MB
    float*  bcat = (float*)VTb;       // alias: bcat dead before VTb written
    __bf16* CTXb = Xb;                // x dead after first GEMM
    __bf16* LATb = QKVb;              // qkv dead after attention
    __bf16* FF1b = QKVb + (size_t)M_ * D_;
    auto WTi = [&](int i) { return WT + (size_t)i * D_ * D_; };

    WPack wp;
    wp.w[0] = W_in; wp.w[1] = Wq; wp.w[2] = Wk; wp.w[3] = Wv;
    wp.w[4] = Wo;   wp.w[5] = W1; wp.w[6] = W2;
    conv_transpose_w<<<dim3(32, 32, 7), dim3(32, 8), 0, stream>>>(wp, WT);
    conv_bf16<<<dim3(4096), dim3(256), 0, stream>>>(x, Xb, (M_ * D_) / 4);
    bcat_k<<<dim3(12), dim3(256), 0, stream>>>(bq, bk, bv, bcat);

    // h = x @ W_in + b_in            (32 m x 16 n = 512 blocks)
    gemm_k<0, 16><<<dim3(512), dim3(256), 0, stream>>>(
        Xb, WTi(0), b_in, nullptr, nullptr, Hb);
    // qkv = h @ [Wq|Wk|Wv] + bcat    (N=3072: 32 x 24 = 768 blocks, 128x128)
    gemm_qkv<<<dim3(768), dim3(256), 0, stream>>>(Hb, WTi(1), bcat, QKVb);
    transpose_v<<<dim3(64, 32, 2), dim3(32, 8), 0, stream>>>(
        QKVb + 2 * D_, VTb, 3 * D_);
    attn_k<<<dim3(1024), dim3(256), 0, stream>>>(
        QKVb, QKVb + D_, VTb, CTXb, 3 * D_);
    // latent = h + s_att * (ctx @ Wo + bo)
    gemm_k<2, 16><<<dim3(512), dim3(256), 0, stream>>>(
        CTXb, WTi(4), bo, Hb, s_att, LATb);
    // ff1 = leaky_relu(latent @ W1 + b1)
    gemm_k<1, 16><<<dim3(512), dim3(256), 0, stream>>>(
        LATb, WTi(5), b1, nullptr, nullptr, FF1b);
    // out = latent + s_ff * (ff1 @ W2 + b2)  (f32)
    gemm_k<3, 16><<<dim3(512), dim3(256), 0, stream>>>(
        FF1b, WTi(6), b2, LATb, s_ff, d_out);
}